// Round 1
// baseline (463.527 us; speedup 1.0000x reference)
//
#include <hip/hip_runtime.h>
#include <math.h>

// Problem constants
#define EPS 1e-8f
// inputs: [B=2, C=32, D=96, H=96, W=96] fp32, pooled to S=8 per axis (12^3 blocks)
// tokens L = 512, channels C = 32

// ---------------------------------------------------------------------------
// Kernel A: adaptive avg-pool 96^3 -> 8^3, write f[inp][b][l][c] (l = z*64+y*8+x)
// grid.x = 8192 = inp(2) * b(2) * c(32) * z(8) * y(8), 256 threads.
// Block covers 12 d-planes x 12 h-rows x 96 w = 13824 floats (54 KB),
// producing 8 outputs (the 8 pooled-x buckets).
//
// v2 (contiguous-lane loads): wave W / iteration k covers an 8-row window
// (rows v8..v8+7, each row = 24 float4). The 192-f4 window starts at a
// multiple of 24, so lane L's three loads q = L, L+64, L+128 have FIXED
// in-row offsets rq_i = q % 24 and FIXED buckets bkt_i = rq_i / 3 across all
// iterations. Per instruction the 64 lanes read 64 consecutive float4
// (>=384B-aligned contiguous segments; fully-consumed 128B lines, no reliance
// on cache retention between instructions — fixes the 48B-stride over-fetch
// of v1). Each lane keeps 3 register accumulators; block-end reduction is
// 3 LDS atomics per thread into acc[8].
// ---------------------------------------------------------------------------
__global__ __launch_bounds__(256) void k_pool(const float* __restrict__ p1,
                                              const float* __restrict__ p2,
                                              float* __restrict__ fpool) {
    int gid = blockIdx.x;
    int y   = gid & 7;
    int z   = (gid >> 3) & 7;
    int c   = (gid >> 6) & 31;
    int b   = (gid >> 11) & 1;
    int inp = gid >> 12;
    const float* p = inp ? p2 : p1;
    const float4* p4 = reinterpret_cast<const float4*>(p);
    // base offset in float4 units (W=96 floats = 24 f4; plane = 9216 floats = 2304 f4)
    int base4 = ((b * 32 + c) * 96 + z * 12) * 2304 + y * 288;

    int t    = threadIdx.x;
    int lane = t & 63;
    int W    = t >> 6;

    // per-lane CONSTANT decomposition of the three loads q = lane + 64*i
    int q0 = lane, q1 = lane + 64, q2 = lane + 128;
    int dq0 = q0 / 24, rq0 = q0 % 24;   // row-within-window, f4-within-row
    int dq1 = q1 / 24, rq1 = q1 % 24;
    int dq2 = q2 / 24, rq2 = q2 % 24;
    int bk0 = rq0 / 3, bk1 = rq1 / 3, bk2 = rq2 / 3;  // pooled-x bucket (fixed!)

    float s0 = 0.f, s1 = 0.f, s2 = 0.f;
    // wave W handles windows v8 = W*8 + 32k < 144 (rows v = d*12 + h)
    for (int v8 = W * 8; v8 < 144; v8 += 32) {
        int va = v8 + dq0, vb = v8 + dq1, vc = v8 + dq2;
        int a0 = base4 + (va / 12) * 2304 + (va % 12) * 24 + rq0;
        int a1 = base4 + (vb / 12) * 2304 + (vb % 12) * 24 + rq1;
        int a2 = base4 + (vc / 12) * 2304 + (vc % 12) * 24 + rq2;
        float4 x0 = p4[a0];
        float4 x1 = p4[a1];
        float4 x2 = p4[a2];
        s0 += (x0.x + x0.y) + (x0.z + x0.w);
        s1 += (x1.x + x1.y) + (x1.z + x1.w);
        s2 += (x2.x + x2.y) + (x2.z + x2.w);
    }

    __shared__ float acc[8];
    if (t < 8) acc[t] = 0.f;
    __syncthreads();
    atomicAdd(&acc[bk0], s0);
    atomicAdd(&acc[bk1], s1);
    atomicAdd(&acc[bk2], s2);
    __syncthreads();
    if (t < 8) {
        int l = z * 64 + y * 8 + t;
        fpool[(((inp * 2 + b) * 512 + l) << 5) + c] = acc[t] * (1.f / 1728.f);
    }
}

// ---------------------------------------------------------------------------
// Kernel B: per-token L2 norms over 32 channels. 2048 tokens total.
// Also zeroes the scalar output (d_out is poisoned 0xAA before every launch).
// grid = 8 blocks x 256 threads.
// ---------------------------------------------------------------------------
__global__ __launch_bounds__(256) void k_norm(const float* __restrict__ fpool,
                                              float* __restrict__ nrm,
                                              float* __restrict__ out) {
    int idx = blockIdx.x * 256 + threadIdx.x;  // [0,2048)
    if (idx == 0) out[0] = 0.f;
    const float4* f4 = reinterpret_cast<const float4*>(fpool + idx * 32);
    float s = 0.f;
#pragma unroll
    for (int i = 0; i < 8; i++) {
        float4 v = f4[i];
        s += v.x * v.x + v.y * v.y + v.z * v.z + v.w * v.w;
    }
    nrm[idx] = sqrtf(s);
}

// ---------------------------------------------------------------------------
// Kernel C: pairwise cosine sims for both inputs + accumulate MSE.
// grid = (32 m-tiles, 32 l-tiles, 2 batches), 256 threads = 16x16 pairs.
// LDS tiles padded [16][33]: unpadded stride-32 gives a 16-way bank conflict
// on the column operand; +1 pad makes both operands conflict-free.
// ---------------------------------------------------------------------------
__global__ __launch_bounds__(256) void k_loss(const float* __restrict__ fpool,
                                              const float* __restrict__ nrm,
                                              float* __restrict__ out) {
    int b  = blockIdx.z;
    int lt = blockIdx.y * 16;
    int mt = blockIdx.x * 16;

    __shared__ float Al[16][33], Am[16][33], Bl[16][33], Bm[16][33];
    __shared__ float nAl[16], nAm[16], nBl[16], nBm[16];

    int t = threadIdx.x;
    int row = t >> 4;
    int c0 = (t & 15) << 1;  // two consecutive channels per thread
    const float2* f2 = reinterpret_cast<const float2*>(fpool);
    int h = c0 >> 1;
    int oAl = ((0 * 2 + b) * 512 + lt + row) * 16 + h;
    int oAm = ((0 * 2 + b) * 512 + mt + row) * 16 + h;
    int oBl = ((1 * 2 + b) * 512 + lt + row) * 16 + h;
    int oBm = ((1 * 2 + b) * 512 + mt + row) * 16 + h;
    float2 v;
    v = f2[oAl]; Al[row][c0] = v.x; Al[row][c0 + 1] = v.y;
    v = f2[oAm]; Am[row][c0] = v.x; Am[row][c0 + 1] = v.y;
    v = f2[oBl]; Bl[row][c0] = v.x; Bl[row][c0 + 1] = v.y;
    v = f2[oBm]; Bm[row][c0] = v.x; Bm[row][c0 + 1] = v.y;
    if (t < 16) {
        nAl[t] = nrm[(0 * 2 + b) * 512 + lt + t];
        nAm[t] = nrm[(0 * 2 + b) * 512 + mt + t];
        nBl[t] = nrm[(1 * 2 + b) * 512 + lt + t];
        nBm[t] = nrm[(1 * 2 + b) * 512 + mt + t];
    }
    __syncthreads();

    int tl = t >> 4, tm = t & 15;
    float da = 0.f, db = 0.f;
#pragma unroll
    for (int c = 0; c < 32; c++) {
        da += Al[tl][c] * Am[tm][c];
        db += Bl[tl][c] * Bm[tm][c];
    }
    float dena = fmaxf(nAl[tl] * nAm[tm], EPS);
    float denb = fmaxf(nBl[tl] * nBm[tm], EPS);
    float diff = da / dena - db / denb;
    float val = diff * diff * (1.f / (512.f * 512.f * 2.f));

    // block reduction -> one atomic per block
#pragma unroll
    for (int m = 1; m < 64; m <<= 1) val += __shfl_xor(val, m);
    __shared__ float red[4];
    if ((t & 63) == 0) red[t >> 6] = val;
    __syncthreads();
    if (t == 0) atomicAdd(out, red[0] + red[1] + red[2] + red[3]);
}

extern "C" void kernel_launch(void* const* d_in, const int* in_sizes, int n_in,
                              void* d_out, int out_size, void* d_ws, size_t ws_size,
                              hipStream_t stream) {
    const float* p1 = (const float*)d_in[0];
    const float* p2 = (const float*)d_in[1];
    float* out = (float*)d_out;

    // workspace layout: fpool [2][2][512][32] floats (256 KB), then nrm [2048] floats
    float* fpool = (float*)d_ws;
    float* nrm = fpool + 2 * 2 * 512 * 32;

    k_pool<<<8192, 256, 0, stream>>>(p1, p2, fpool);
    k_norm<<<8, 256, 0, stream>>>(fpool, nrm, out);
    k_loss<<<dim3(32, 32, 2), 256, 0, stream>>>(fpool, nrm, out);
}

// Round 2
// 437.794 us; speedup vs baseline: 1.0588x; 1.0588x over previous
//
#include <hip/hip_runtime.h>
#include <math.h>

#define EPS 1e-8f
// inputs: [B=2, C=32, D=96, H=96, W=96] fp32, pooled to S=8 per axis (12^3 blocks)
// tokens L = 512, channels C = 32

// ---------------------------------------------------------------------------
// Kernel A v3: adaptive avg-pool 96^3 -> 8^3, write f[inp][b][l][c].
// grid.x = 4096 = inp(2) * b(2) * cc(16) * z(8) * y(8), 256 threads.
// Each block covers TWO c-slabs (c = cc and cc+16), 108 KB total.
// Wave W: slab s = W>>1, window-half = W&1; exactly 9 windows of 8 rows each
// (uniform trip count). Lane L's three streams q = L, L+64, L+128 have
// lane-constant in-row offset rq (=> fixed pooled-x bucket) and the
// row-advance carry pattern has period 3, so the j->j+1 address deltas are
// precomputed per lane (e1, e2) and the 3-window group stride is the
// compile-time constant 4608 f4 (= 2 planes). Full unroll => 9 loads in
// flight per wave, zero divides / zero branches in the hot loop.
// Each wave-instruction still reads 64 consecutive float4 (coalesced 1KB).
// ---------------------------------------------------------------------------
__global__ __launch_bounds__(256) void k_pool(const float* __restrict__ p1,
                                              const float* __restrict__ p2,
                                              float* __restrict__ fpool,
                                              float* __restrict__ out) {
    int gid = blockIdx.x;
    int y   = gid & 7;
    int z   = (gid >> 3) & 7;
    int cc  = (gid >> 6) & 15;
    int b   = (gid >> 10) & 1;
    int inp = gid >> 11;
    const float4* p4 = reinterpret_cast<const float4*>(inp ? p2 : p1);

    int t    = threadIdx.x;
    int lane = t & 63;
    int W    = t >> 6;
    int s    = W >> 1;   // which c-slab
    int half = W & 1;    // which 9-window half (rows 0-71 vs 72-143)

    if (gid == 0 && t == 0) out[0] = 0.f;  // d_out poisoned before each launch

    // base in float4 units: W=96 floats = 24 f4; plane = 2304 f4
    int base4 = ((b * 32 + cc + s * 16) * 96 + z * 12) * 2304 + y * 288
              + half * 13824;  // 72 rows = 6 planes

    // lane-constant stream decomposition: q = lane + 64*i
    int q0 = lane, q1 = lane + 64, q2 = lane + 128;
    int dq0 = q0 / 24, rq0 = q0 - dq0 * 24;
    int dq1 = q1 / 24, rq1 = q1 - dq1 * 24;
    int dq2 = q2 / 24, rq2 = q2 - dq2 * 24;
    int bk0 = rq0 / 3, bk1 = rq1 / 3, bk2 = rq2 / 3;  // pooled-x bucket (fixed)

    int a0 = base4 + q0, a1 = base4 + q1, a2 = base4 + q2;

    // per-stream cumulative deltas for j -> j+1 -> j+2 inside a 3-window group.
    // row-advance: h += 8; on carry (h>=12 after add): h -= 12, d += 1.
    // delta f4 = 192 (no carry) or 2208 (carry). Sum over 3 steps is always 4608.
    auto mkdel = [](int h0, int& e1, int& e2) {
        int n1 = h0 + 8;
        int d1 = (n1 >= 12) ? 2208 : 192;
        int h1 = (n1 >= 12) ? n1 - 12 : n1;
        int n2 = h1 + 8;
        int d2 = (n2 >= 12) ? 2208 : 192;
        e1 = d1; e2 = d1 + d2;
    };
    int e10, e20, e11, e21, e12, e22;
    mkdel(dq0, e10, e20);
    mkdel(dq1, e11, e21);
    mkdel(dq2, e12, e22);

    float s0 = 0.f, s1 = 0.f, s2 = 0.f;
#pragma unroll
    for (int g = 0; g < 3; ++g) {
        int b0 = a0 + g * 4608, b1 = a1 + g * 4608, b2 = a2 + g * 4608;
        float4 x0a = p4[b0], x0b = p4[b0 + e10], x0c = p4[b0 + e20];
        float4 x1a = p4[b1], x1b = p4[b1 + e11], x1c = p4[b1 + e21];
        float4 x2a = p4[b2], x2b = p4[b2 + e12], x2c = p4[b2 + e22];
        s0 += ((x0a.x + x0a.y) + (x0a.z + x0a.w))
            + ((x0b.x + x0b.y) + (x0b.z + x0b.w))
            + ((x0c.x + x0c.y) + (x0c.z + x0c.w));
        s1 += ((x1a.x + x1a.y) + (x1a.z + x1a.w))
            + ((x1b.x + x1b.y) + (x1b.z + x1b.w))
            + ((x1c.x + x1c.y) + (x1c.z + x1c.w));
        s2 += ((x2a.x + x2a.y) + (x2a.z + x2a.w))
            + ((x2b.x + x2b.y) + (x2b.z + x2b.w))
            + ((x2c.x + x2c.y) + (x2c.z + x2c.w));
    }

    __shared__ float acc[2][8];
    if (t < 16) acc[t >> 3][t & 7] = 0.f;
    __syncthreads();
    atomicAdd(&acc[s][bk0], s0);
    atomicAdd(&acc[s][bk1], s1);
    atomicAdd(&acc[s][bk2], s2);
    __syncthreads();
    if (t < 16) {
        int ss = t >> 3, x = t & 7;
        int l = z * 64 + y * 8 + x;
        fpool[(((inp * 2 + b) * 512 + l) << 5) + cc + ss * 16] = acc[ss][x] * (1.f / 1728.f);
    }
}

// ---------------------------------------------------------------------------
// Kernel B v2: pairwise cosine sims + MSE, norms fused (k_norm eliminated).
// grid = (16, 16, 2) = 512 blocks, 256 threads. 32x32 output tile per block,
// 2x2 register blocking per thread, K = 32 channels.
// LDS rows padded to 36 floats: 16B-aligned float4 access, conflict-free
// (each row-octet of lanes covers all 32 banks).
// ---------------------------------------------------------------------------
#define FMA4(A, U, V) do { A.x += U.x * V.x; A.y += U.y * V.y; \
                           A.z += U.z * V.z; A.w += U.w * V.w; } while (0)

__global__ __launch_bounds__(256) void k_loss(const float* __restrict__ fpool,
                                              float* __restrict__ out) {
    int b  = blockIdx.z;
    int lt = blockIdx.y * 32;
    int mt = blockIdx.x * 32;

    __shared__ float Al[32][36], Am[32][36], Bl[32][36], Bm[32][36];
    __shared__ float nAl[32], nAm[32], nBl[32], nBm[32];

    int t = threadIdx.x;
    int row = t >> 3, fp = t & 7;   // 32 rows x 8 float4 per tile
    const float4* f4 = reinterpret_cast<const float4*>(fpool);
    float4 v;
    v = f4[((0 * 2 + b) * 512 + lt + row) * 8 + fp];
    *reinterpret_cast<float4*>(&Al[row][fp << 2]) = v;
    v = f4[((0 * 2 + b) * 512 + mt + row) * 8 + fp];
    *reinterpret_cast<float4*>(&Am[row][fp << 2]) = v;
    v = f4[((1 * 2 + b) * 512 + lt + row) * 8 + fp];
    *reinterpret_cast<float4*>(&Bl[row][fp << 2]) = v;
    v = f4[((1 * 2 + b) * 512 + mt + row) * 8 + fp];
    *reinterpret_cast<float4*>(&Bm[row][fp << 2]) = v;
    __syncthreads();

    // fused per-token L2 norms (was kernel k_norm)
    if (t < 128) {
        int which = t >> 5, r = t & 31;
        const float* rowp = (which == 0 ? Al[r] : which == 1 ? Am[r]
                           : which == 2 ? Bl[r] : Bm[r]);
        float ssum = 0.f;
#pragma unroll
        for (int fc = 0; fc < 8; ++fc) {
            float4 u = *reinterpret_cast<const float4*>(&rowp[fc << 2]);
            ssum += u.x * u.x + u.y * u.y + u.z * u.z + u.w * u.w;
        }
        float* np = (which == 0 ? nAl : which == 1 ? nAm
                   : which == 2 ? nBl : nBm);
        np[r] = sqrtf(ssum);
    }
    __syncthreads();

    int tl = t >> 4, tm = t & 15;
    float4 da00 = {0.f,0.f,0.f,0.f}, da01 = {0.f,0.f,0.f,0.f};
    float4 da10 = {0.f,0.f,0.f,0.f}, da11 = {0.f,0.f,0.f,0.f};
    float4 db00 = {0.f,0.f,0.f,0.f}, db01 = {0.f,0.f,0.f,0.f};
    float4 db10 = {0.f,0.f,0.f,0.f}, db11 = {0.f,0.f,0.f,0.f};
#pragma unroll
    for (int fc = 0; fc < 8; ++fc) {
        float4 al0 = *reinterpret_cast<const float4*>(&Al[tl][fc << 2]);
        float4 al1 = *reinterpret_cast<const float4*>(&Al[tl + 16][fc << 2]);
        float4 am0 = *reinterpret_cast<const float4*>(&Am[tm][fc << 2]);
        float4 am1 = *reinterpret_cast<const float4*>(&Am[tm + 16][fc << 2]);
        float4 bl0 = *reinterpret_cast<const float4*>(&Bl[tl][fc << 2]);
        float4 bl1 = *reinterpret_cast<const float4*>(&Bl[tl + 16][fc << 2]);
        float4 bm0 = *reinterpret_cast<const float4*>(&Bm[tm][fc << 2]);
        float4 bm1 = *reinterpret_cast<const float4*>(&Bm[tm + 16][fc << 2]);
        FMA4(da00, al0, am0); FMA4(da01, al0, am1);
        FMA4(da10, al1, am0); FMA4(da11, al1, am1);
        FMA4(db00, bl0, bm0); FMA4(db01, bl0, bm1);
        FMA4(db10, bl1, bm0); FMA4(db11, bl1, bm1);
    }
    float ta00 = (da00.x + da00.y) + (da00.z + da00.w);
    float ta01 = (da01.x + da01.y) + (da01.z + da01.w);
    float ta10 = (da10.x + da10.y) + (da10.z + da10.w);
    float ta11 = (da11.x + da11.y) + (da11.z + da11.w);
    float tb00 = (db00.x + db00.y) + (db00.z + db00.w);
    float tb01 = (db01.x + db01.y) + (db01.z + db01.w);
    float tb10 = (db10.x + db10.y) + (db10.z + db10.w);
    float tb11 = (db11.x + db11.y) + (db11.z + db11.w);

    float nal0 = nAl[tl], nal1 = nAl[tl + 16];
    float nam0 = nAm[tm], nam1 = nAm[tm + 16];
    float nbl0 = nBl[tl], nbl1 = nBl[tl + 16];
    float nbm0 = nBm[tm], nbm1 = nBm[tm + 16];

    float d00 = ta00 / fmaxf(nal0 * nam0, EPS) - tb00 / fmaxf(nbl0 * nbm0, EPS);
    float d01 = ta01 / fmaxf(nal0 * nam1, EPS) - tb01 / fmaxf(nbl0 * nbm1, EPS);
    float d10 = ta10 / fmaxf(nal1 * nam0, EPS) - tb10 / fmaxf(nbl1 * nbm0, EPS);
    float d11 = ta11 / fmaxf(nal1 * nam1, EPS) - tb11 / fmaxf(nbl1 * nbm1, EPS);
    float val = (d00 * d00 + d01 * d01 + d10 * d10 + d11 * d11)
              * (1.f / (512.f * 512.f * 2.f));

    // block reduction -> one atomic per block (512 atomics total)
#pragma unroll
    for (int m = 1; m < 64; m <<= 1) val += __shfl_xor(val, m);
    __shared__ float red[4];
    if ((t & 63) == 0) red[t >> 6] = val;
    __syncthreads();
    if (t == 0) atomicAdd(out, red[0] + red[1] + red[2] + red[3]);
}

extern "C" void kernel_launch(void* const* d_in, const int* in_sizes, int n_in,
                              void* d_out, int out_size, void* d_ws, size_t ws_size,
                              hipStream_t stream) {
    const float* p1 = (const float*)d_in[0];
    const float* p2 = (const float*)d_in[1];
    float* out = (float*)d_out;

    // workspace layout: fpool [2][2][512][32] floats (256 KB)
    float* fpool = (float*)d_ws;

    k_pool<<<4096, 256, 0, stream>>>(p1, p2, fpool, out);
    k_loss<<<dim3(16, 16, 2), 256, 0, stream>>>(fpool, out);
}